// Round 1
// 320.902 us; speedup vs baseline: 1.2514x; 1.2514x over previous
//
#include <hip/hip_runtime.h>

// LocallyConnected2D: y[n,h,w] = relu(sum_{i,j} x[n,h+i,w+j]*W[h,w,i,j] + b[h,w])
// lane = batch n (N=64=wave). History:
//  R1: scalar (SMEM) weights -> lgkmcnt drains mixed with ds_read. Clean regs.
//  R2: f[12] local array -> scratch (223MB writes).
//  R3: VMEM uniform weights + full unroll -> hoist pressure -> spill (191MB).
//  R4: weights via LDS broadcast (full unroll) -> hoisted ds_reads, spill.
//  R5: manual cur/nxt prefetch + memory clobber -> arrays in scratch (1.78GB).
//  R6: sched_barrier(0x7) regions -> allocator catastrophe (3.68GB scratch).
//  R7: runtime r loop (unroll 1), weights as per-iter uniform VMEM loads.
//      284 us. Counters: VALUBusy 17%, HBM 15%, occ 31% -> latency-bound on
//      9 serialized cold weight-load stalls per wave (weights are read-once,
//      every load is an HBM miss ~900cy, issued 24-small-loads-then-drain).
//  R8 (this): weights bulk-staged to LDS in the SAME high-MLP burst as the
//      x tile (coalesced dwordx4 + permuted scatter to [r][72] layout).
//      Main loop = pure LDS+VALU: 18 aligned broadcast ds_read_b128 (weights)
//      + 4 ds_read_b128 (x) per iteration, zero global loads, all-DS lgkmcnt
//      (no SMEM mixing). Runtime r loop retained to bound scheduler region.

#define H_IN 512
#define W_IN 512
#define H_OUT 504
#define W_OUT 504
#define W_T 8
#define H_T 4
#define NW 4                  // waves per block
#define TROWS (H_T + 8)       // 12 staged input rows
#define XF (TROWS * 1024)     // 12288 floats = 48 KB
#define WPW (81 * W_T)        // 648 weight floats per wave
#define WF (NW * WPW)         // 2592 floats = 10368 B ; total LDS 59520 B -> 2 blocks/CU

// 4-byte-aligned float4: legal C++ for unaligned-by-16 global loads
typedef float f4u __attribute__((ext_vector_type(4), aligned(4)));

__launch_bounds__(256, 2)
__global__ void lc2d_kernel(const float* __restrict__ x,
                            const float* __restrict__ weight,
                            const float* __restrict__ bias,
                            float* __restrict__ out) {
    __shared__ float lds[XF + WF];  // x tile [row][wq][n][4] then weights [wv][r][72]

    const int t    = threadIdx.x;
    const int lane = t & 63;          // batch index n (compute phase)
    const int wv   = t >> 6;          // wave 0..3

    const int h0 = blockIdx.y * H_T;
    const int w0 = blockIdx.x * W_T;

    // ---- stage x tile; thread t = (n = t>>2, wq = t&3) ----
    // global: 4 consecutive float4 per n (64B chunks); LDS write row*1024+wq*256+n*4
    {
        const int n  = t >> 2;
        const int wq = t & 3;
        const float* gx = x + (size_t)n * (H_IN * W_IN)
                            + (size_t)h0 * W_IN + w0 + wq * 4;
        float* ld = &lds[wq * 256 + n * 4];
        #pragma unroll
        for (int row = 0; row < TROWS; ++row) {
            const float4 v = *reinterpret_cast<const float4*>(gx + row * W_IN);
            *reinterpret_cast<float4*>(ld + row * 1024) = v;
        }
    }

    // ---- stage weights: 4 chunks of 648 contiguous floats (162 float4 each),
    // coalesced dwordx4 reads issued alongside the x loads (deep MLP, one-time),
    // scatter-written to permuted LDS layout  lds[XF + cw*648 + r*72 + (k*9+tp)]
    // so compute reads are 18 aligned broadcast b128 per iteration.
    #pragma unroll
    for (int i = 0; i < 3; ++i) {
        const int c = t + i * 256;            // float4 chunk id, < 648
        if (c < NW * 162) {                   // i=2: only t<136
            const int cw  = c / 162;          // which wave's chunk (magic-mul)
            const int rm4 = c - cw * 162;
            const f4u v = *reinterpret_cast<const f4u*>(
                weight + ((size_t)(h0 + cw) * W_OUT + w0) * 81 + rm4 * 4);
            #pragma unroll
            for (int e = 0; e < 4; ++e) {
                const int rem = rm4 * 4 + e;          // linear k*81 + r*9 + tp
                const int k   = rem / 81;
                const int r9  = rem - k * 81;
                const int r2  = r9 / 9;
                const int tp  = r9 - r2 * 9;
                lds[XF + cw * WPW + r2 * 72 + k * 9 + tp] = v[e];
            }
        }
    }

    __syncthreads();

    const int wvu = __builtin_amdgcn_readfirstlane(wv);
    const int h   = h0 + wvu;                      // this wave's output row

    float acc[W_T];
    {
        const float* bptr = bias + (size_t)h * W_OUT + w0;   // uniform: s_load
        #pragma unroll
        for (int k = 0; k < W_T; ++k) acc[k] = bptr[k];
    }

    const float* xl = &lds[wvu * 1024 + lane * 4];     // x row base, +1024/iter
    const float* wl = &lds[XF + wvu * WPW];            // weight row base, +72/iter

    #pragma unroll 1
    for (int r = 0; r < 9; ++r) {
        // weights for this tap-row: 72 floats via 18 broadcast ds_read_b128
        // (wave-uniform address -> same-address broadcast, conflict-free)
        float wr[72];
        #pragma unroll
        for (int i = 0; i < 18; ++i) {
            const float4 v = *reinterpret_cast<const float4*>(wl + i * 4);
            wr[4 * i + 0] = v.x; wr[4 * i + 1] = v.y;
            wr[4 * i + 2] = v.z; wr[4 * i + 3] = v.w;
        }

        // x row (wv + r): 16 floats/lane via 4 conflict-free ds_read_b128
        float xr[16];
        #pragma unroll
        for (int c = 0; c < 4; ++c) {
            const float4 v = *reinterpret_cast<const float4*>(xl + c * 256);
            xr[4 * c + 0] = v.x; xr[4 * c + 1] = v.y;
            xr[4 * c + 2] = v.z; xr[4 * c + 3] = v.w;
        }

        #pragma unroll
        for (int k = 0; k < W_T; ++k) {
            #pragma unroll
            for (int tp = 0; tp < 9; ++tp)
                acc[k] = fmaf(wr[k * 9 + tp], xr[k + tp], acc[k]);
        }

        xl += 1024;     // next x row
        wl += 72;       // next tap-row of weights
    }

    // ---- epilogue: ReLU + store (1 row x 8 floats per lane, 16B-aligned) ----
    float* o = out + (size_t)lane * (H_OUT * W_OUT) + (size_t)h * W_OUT + w0;
    float4 s;
    s.x = fmaxf(acc[0], 0.f); s.y = fmaxf(acc[1], 0.f);
    s.z = fmaxf(acc[2], 0.f); s.w = fmaxf(acc[3], 0.f);
    *reinterpret_cast<float4*>(o) = s;
    s.x = fmaxf(acc[4], 0.f); s.y = fmaxf(acc[5], 0.f);
    s.z = fmaxf(acc[6], 0.f); s.w = fmaxf(acc[7], 0.f);
    *reinterpret_cast<float4*>(o + 4) = s;
}

extern "C" void kernel_launch(void* const* d_in, const int* in_sizes, int n_in,
                              void* d_out, int out_size, void* d_ws, size_t ws_size,
                              hipStream_t stream) {
    const float* x      = (const float*)d_in[0];
    const float* weight = (const float*)d_in[1];
    const float* bias   = (const float*)d_in[2];
    float* out          = (float*)d_out;

    dim3 grid(W_OUT / W_T, H_OUT / H_T);   // 63 x 126
    dim3 block(256);
    lc2d_kernel<<<grid, block, 0, stream>>>(x, weight, bias, out);
}

// Round 2
// 290.912 us; speedup vs baseline: 1.3804x; 1.1031x over previous
//
#include <hip/hip_runtime.h>

// LocallyConnected2D: y[n,h,w] = relu(sum_{i,j} x[n,h+i,w+j]*W[h,w,i,j] + b[h,w])
// lane = batch n (N=64=wave). History:
//  R1: scalar (SMEM) weights -> lgkmcnt drains mixed with ds_read. Clean regs.
//  R2: f[12] local array -> scratch (223MB writes).
//  R3: VMEM uniform weights + full unroll -> hoist pressure -> spill (191MB).
//  R4: weights via LDS broadcast (full unroll) -> hoisted ds_reads, spill.
//  R5: manual cur/nxt prefetch + memory clobber -> arrays in scratch (1.78GB).
//  R6: sched_barrier(0x7) regions -> allocator catastrophe (3.68GB scratch).
//  R7: runtime r loop, weights as per-iter uniform VMEM loads. 284us.
//  R8: weights bulk-staged to LDS, 18 broadcast ds_read_b128/iter. 205us.
//      Counters: VALUBusy 29%, HBM 20%, occ 21.5%, LDS_BANK_CONFLICT 2.2e7.
//      Budget: 162 bcast b128/wave on the shared per-CU LDS pipe ~= half the
//      round time; broadcasts move 16B unique data each. LDS-pipe-bound.
//  R9 (this): weights NEVER touch LDS. Per-wave gather global->18 VGPRs in
//      padded pack p=q*16+r (reg=q>>2 compile-time, lane=16(q&3)+r uniform).
//      Hot loop: v_readlane (VALU, 4 SIMDs in parallel) + v_fmac (SGPR src).
//      LDS = x tile only (48KB) -> 3 blocks/CU. x staging writes XOR-swizzled
//      (n*4 ^ wq*4) to kill the 4-way bank conflict; reads use the same XOR.

#define H_IN 512
#define W_IN 512
#define H_OUT 504
#define W_OUT 504
#define W_T 8
#define H_T 4
#define TROWS (H_T + 8)       // 12 staged input rows
#define XF (TROWS * 1024)     // 12288 floats = 48 KB -> 3 blocks/CU

__device__ __forceinline__ float readlane_f(float v, int l) {
    return __int_as_float(__builtin_amdgcn_readlane(__float_as_int(v), l));
}

__launch_bounds__(256, 3)
__global__ void lc2d_kernel(const float* __restrict__ x,
                            const float* __restrict__ weight,
                            const float* __restrict__ bias,
                            float* __restrict__ out) {
    __shared__ float lds[XF];   // x tile: [row][wq][ (n*4)^(wq*4) ] swizzled

    const int t    = threadIdx.x;
    const int lane = t & 63;          // batch index n (compute phase)
    const int wv   = t >> 6;          // wave 0..3

    const int h0 = blockIdx.y * H_T;
    const int w0 = blockIdx.x * W_T;

    // ---- stage x tile; thread t = (n = t>>2, wq = t&3) ----
    // global: 4 consecutive float4 per n (64B chunks, coalesced)
    // LDS write byte addr = row*4096 + wq*1024 + (n*16 ^ wq*16): start banks
    // (4n ^ 4wq)%32 hit 2 lanes/bank (free) instead of 4-way conflict.
    {
        const int n  = t >> 2;
        const int wq = t & 3;
        const float* gx = x + (size_t)n * (H_IN * W_IN)
                            + (size_t)h0 * W_IN + w0 + wq * 4;
        float* ld = &lds[wq * 256 + ((n * 4) ^ (wq * 4))];
        #pragma unroll
        for (int row = 0; row < TROWS; ++row) {
            const float4 v = *reinterpret_cast<const float4*>(gx + row * W_IN);
            *reinterpret_cast<float4*>(ld + row * 1024) = v;
        }
    }

    // ---- weights: per-wave gather global -> 18 VGPRs, packed p = q*16 + rr
    // (q = k*9+tp in 0..71, rr = tap row, slots rr=9..15 padding).
    // reg d = p>>6 (0..17, compile-time at use), lane = p&63 = 16*(q&3)+rr.
    // Inverse at load: q = 4d + (l>>4), rr = l&15. Issued in the same burst
    // as the x loads -> cold-miss latency overlapped; zero LDS involvement.
    float wpk[18];
    {
        const float* wb = weight + ((size_t)(h0 + wv) * W_OUT + w0) * 81;
        const int qb = lane >> 4;     // 0..3
        const int rr = lane & 15;
        #pragma unroll
        for (int d = 0; d < 18; ++d) {
            const int q  = 4 * d + qb;        // 0..71
            const int k  = q / 9;             // magic-mul, one-time
            const int tp = q - 9 * k;
            float v = 0.f;
            if (rr < 9) v = wb[k * 81 + rr * 9 + tp];
            wpk[d] = v;
        }
    }

    __syncthreads();

    const int wvu = __builtin_amdgcn_readfirstlane(wv);
    const int h   = h0 + wvu;                      // this wave's output row

    float acc[W_T];
    {
        const float* bptr = bias + (size_t)h * W_OUT + w0;   // uniform: s_load
        #pragma unroll
        for (int k = 0; k < W_T; ++k) acc[k] = bptr[k];
    }

    // 4 swizzled x chunk pointers for this lane; row offset advances 1024/iter
    const float* xp0 = &lds[0 * 256 + ((lane * 4) ^ 0)  + wvu * 1024];
    const float* xp1 = &lds[1 * 256 + ((lane * 4) ^ 4)  + wvu * 1024];
    const float* xp2 = &lds[2 * 256 + ((lane * 4) ^ 8)  + wvu * 1024];
    const float* xp3 = &lds[3 * 256 + ((lane * 4) ^ 12) + wvu * 1024];

    #pragma unroll 1
    for (int r = 0; r < 9; ++r) {
        // x row (wv + r): 16 floats/lane via 4 conflict-free ds_read_b128
        float xr[16];
        {
            const float4 v0 = *reinterpret_cast<const float4*>(xp0);
            const float4 v1 = *reinterpret_cast<const float4*>(xp1);
            const float4 v2 = *reinterpret_cast<const float4*>(xp2);
            const float4 v3 = *reinterpret_cast<const float4*>(xp3);
            xr[0] = v0.x; xr[1] = v0.y; xr[2]  = v0.z; xr[3]  = v0.w;
            xr[4] = v1.x; xr[5] = v1.y; xr[6]  = v1.z; xr[7]  = v1.w;
            xr[8] = v2.x; xr[9] = v2.y; xr[10] = v2.z; xr[11] = v2.w;
            xr[12] = v3.x; xr[13] = v3.y; xr[14] = v3.z; xr[15] = v3.w;
        }

        // uniform readlane indices for this tap-row (4 SGPR adds)
        const int li0 = r;
        const int li1 = r + 16;
        const int li2 = r + 32;
        const int li3 = r + 48;

        // tp outer / k inner: consecutive fmacs hit different acc chains
        #pragma unroll
        for (int tp = 0; tp < 9; ++tp) {
            #pragma unroll
            for (int k = 0; k < W_T; ++k) {
                const int q  = k * 9 + tp;          // compile-time
                const int qm = q & 3;
                const int li = (qm == 0) ? li0 : (qm == 1) ? li1
                             : (qm == 2) ? li2 : li3;
                const float w = readlane_f(wpk[q >> 2], li);
                acc[k] = fmaf(w, xr[k + tp], acc[k]);
            }
        }

        xp0 += 1024; xp1 += 1024; xp2 += 1024; xp3 += 1024;
    }

    // ---- epilogue: ReLU + store (1 row x 8 floats per lane, 16B-aligned) ----
    float* o = out + (size_t)lane * (H_OUT * W_OUT) + (size_t)h * W_OUT + w0;
    float4 s;
    s.x = fmaxf(acc[0], 0.f); s.y = fmaxf(acc[1], 0.f);
    s.z = fmaxf(acc[2], 0.f); s.w = fmaxf(acc[3], 0.f);
    *reinterpret_cast<float4*>(o) = s;
    s.x = fmaxf(acc[4], 0.f); s.y = fmaxf(acc[5], 0.f);
    s.z = fmaxf(acc[6], 0.f); s.w = fmaxf(acc[7], 0.f);
    *reinterpret_cast<float4*>(o + 4) = s;
}

extern "C" void kernel_launch(void* const* d_in, const int* in_sizes, int n_in,
                              void* d_out, int out_size, void* d_ws, size_t ws_size,
                              hipStream_t stream) {
    const float* x      = (const float*)d_in[0];
    const float* weight = (const float*)d_in[1];
    const float* bias   = (const float*)d_in[2];
    float* out          = (float*)d_out;

    dim3 grid(W_OUT / W_T, H_OUT / H_T);   // 63 x 126
    dim3 block(256);
    lc2d_kernel<<<grid, block, 0, stream>>>(x, weight, bias, out);
}